// Round 2
// baseline (1950.819 us; speedup 1.0000x reference)
//
#include <hip/hip_runtime.h>
#include <hip/hip_cooperative_groups.h>
#include <math.h>

namespace cg = cooperative_groups;

// B=128, R=4608, K=2, O=32, I=16.  lane=ko, thread owns 32 b x 9 r.
// ws float layout: s0,s1,s2 [128*64]; bij0,bij1 [4608*2]
#define S_SZ   8192
#define BIJ_SZ 9216

__device__ __forceinline__ float bf_lo(unsigned p) { return __uint_as_float(p << 16); }
__device__ __forceinline__ float bf_hi(unsigned p) { return __uint_as_float(p & 0xffff0000u); }
__device__ __forceinline__ unsigned pack_bf16(float a, float b) {
    unsigned ua = __float_as_uint(a);
    unsigned ub = __float_as_uint(b);
    ua += 0x7fffu + ((ua >> 16) & 1u);   // RNE
    ub += 0x7fffu + ((ub >> 16) & 1u);
    return (ua >> 16) | (ub & 0xffff0000u);
}

__device__ __forceinline__ float dot16(const float4 w0, const float4 w1,
                                       const float4 w2, const float4 w3,
                                       const float* __restrict__ xp) {
    float4 a0 = *(const float4*)(xp + 0);
    float4 a1 = *(const float4*)(xp + 4);
    float4 a2 = *(const float4*)(xp + 8);
    float4 a3 = *(const float4*)(xp + 12);
    return w0.x*a0.x + w0.y*a0.y + w0.z*a0.z + w0.w*a0.w
         + w1.x*a1.x + w1.y*a1.y + w1.z*a1.z + w1.w*a1.w
         + w2.x*a2.x + w2.y*a2.y + w2.z*a2.z + w2.w*a2.w
         + w3.x*a3.x + w3.y*a3.y + w3.z*a3.z + w3.w*a3.w;
}

__global__ __launch_bounds__(512, 2) void caps_mega(
    const float* __restrict__ x, const float* __restrict__ W,
    float* __restrict__ out, float* __restrict__ ws)
{
    __shared__ float sredL[8 * 32 * 64];   // 64 KB wave-partial s
    __shared__ float red2[512];
    __shared__ float c_lds[72][2];

    float* s0 = ws;
    float* s1 = ws + S_SZ;
    float* s2 = ws + 2 * S_SZ;
    float* bij0 = ws + 3 * S_SZ;
    float* bij1 = ws + 3 * S_SZ + BIJ_SZ;

    const int t    = threadIdx.x;
    const int lane = t & 63;
    const int w    = t >> 6;
    const int bk   = blockIdx.x;
    const int bg   = bk >> 6;          // 0..3  -> b-range
    const int rgB  = bk & 63;          // 0..63 -> r-range
    const int b0   = bg * 32;
    const int rg   = rgB * 8 + w;      // 0..511
    const int r0   = rg * 9;
    const int k    = lane >> 5;
    const int o    = lane & 31;

    // zero s0..s2 + bij0..bij1 (ws is poisoned 0xAA)
    {
        int i = bk * 512 + t;
        if (i < 3 * S_SZ + 2 * BIJ_SZ) ws[i] = 0.0f;
    }

    // ---- phase 0: u_hat[b,r,ko] into registers (bf16 pairs: lo=even b) ----
    unsigned u2[144];
    {
        const float* Wbase = W + (size_t)r0 * 1024 + (size_t)lane * 16;
        const float* xbase = x + ((size_t)b0 * 4608 + (size_t)r0) * 16;
#pragma unroll
        for (int ri = 0; ri < 9; ++ri) {
            float4 w0 = *(const float4*)(Wbase + ri * 1024 + 0);
            float4 w1 = *(const float4*)(Wbase + ri * 1024 + 4);
            float4 w2 = *(const float4*)(Wbase + ri * 1024 + 8);
            float4 w3 = *(const float4*)(Wbase + ri * 1024 + 12);
#pragma unroll
            for (int bp = 0; bp < 16; ++bp) {
                const float* xp = xbase + ((size_t)(2 * bp) * 4608 + ri) * 16;
                const float* xq = xp + (size_t)4608 * 16;
                float accA = dot16(w0, w1, w2, w3, xp);
                float accB = dot16(w0, w1, w2, w3, xq);
                u2[ri * 16 + bp] = pack_bf16(accA, accB);
            }
        }
    }

    cg::grid_group grid = cg::this_grid();
    grid.sync();   // zeroing + (nothing else global yet) visible

    float ccc[9];
    float vv[32];

    // s[b,ko] += sum_r c[r,k]*u  : in-reg over 9 r, LDS tree over 8 waves, atomics over 64 rgB-blocks
    auto do_sred = [&](float* __restrict__ sG) {
        float sp[32];
#pragma unroll
        for (int i = 0; i < 32; ++i) sp[i] = 0.0f;
#pragma unroll
        for (int ri = 0; ri < 9; ++ri) {
            float cc = ccc[ri];
#pragma unroll
            for (int bp = 0; bp < 16; ++bp) {
                unsigned p = u2[ri * 16 + bp];
                sp[2 * bp]     = fmaf(cc, bf_lo(p), sp[2 * bp]);
                sp[2 * bp + 1] = fmaf(cc, bf_hi(p), sp[2 * bp + 1]);
            }
        }
#pragma unroll
        for (int bl = 0; bl < 32; ++bl) sredL[(w * 32 + bl) * 64 + lane] = sp[bl];
        __syncthreads();
        for (int e = t; e < 2048; e += 512) {
            float acc = 0.0f;
#pragma unroll
            for (int ww = 0; ww < 8; ++ww) acc += sredL[ww * 2048 + e];
            atomicAdd(&sG[b0 * 64 + e], acc);
        }
        __syncthreads();
    };

    // v[b,ko] from global s (post-sync): shuffle-reduce sn over the 32 o-lanes of this k-half
    auto compute_v = [&](const float* __restrict__ sG) {
#pragma unroll
        for (int bl = 0; bl < 32; ++bl) {
            float sv = sG[(b0 + bl) * 64 + lane];
            float p = sv * sv;
#pragma unroll
            for (int m = 16; m > 0; m >>= 1) p += __shfl_xor(p, m, 64);
            float f = p / ((0.5f + p) * sqrtf(p));
            vv[bl] = sv * f;
        }
    };

    // bij[r,k] += (1/B) sum_b sum_o u*v : 32 b in-reg, 32 o via shuffle, 4 bg via atomics
    auto do_agree = [&](float* __restrict__ bijG) {
#pragma unroll
        for (int ri = 0; ri < 9; ++ri) {
            float p = 0.0f;
#pragma unroll
            for (int bp = 0; bp < 16; ++bp) {
                unsigned pu = u2[ri * 16 + bp];
                p = fmaf(bf_lo(pu), vv[2 * bp], p);
                p = fmaf(bf_hi(pu), vv[2 * bp + 1], p);
            }
#pragma unroll
            for (int m = 16; m > 0; m >>= 1) p += __shfl_xor(p, m, 64);
            if (o == 0) atomicAdd(&bijG[(r0 + ri) * 2 + k], p * (1.0f / 128.0f));
        }
    };

    // per-block redundant softmax over R (z = bA [+ bB]); fills ccc for this thread's 9 r's
    auto do_softmax = [&](const float* __restrict__ bA, const float* __restrict__ bB) {
        float zloc[18];
        float m = -1e30f;
#pragma unroll
        for (int j = 0; j < 18; ++j) {
            int idx = t + j * 512;
            float z = bA[idx];
            if (bB) z += bB[idx];
            zloc[j] = z;
            m = fmaxf(m, z);
        }
        red2[t] = m;
        __syncthreads();
        for (int off = 256; off >= 2; off >>= 1) {   // parity-preserving tree (k = t&1)
            if (t < off) red2[t] = fmaxf(red2[t], red2[t + off]);
            __syncthreads();
        }
        float mk = red2[t & 1];
        __syncthreads();
        float ssum = 0.0f;
#pragma unroll
        for (int j = 0; j < 18; ++j) ssum += __expf(zloc[j] - mk);
        red2[t] = ssum;
        __syncthreads();
        for (int off = 256; off >= 2; off >>= 1) {
            if (t < off) red2[t] += red2[t + off];
            __syncthreads();
        }
        if (t < 144) {
            int rr = t >> 1, kk = t & 1;          // kk == t&1 == parity used for mk
            int idx = (rgB * 72 + rr) * 2 + kk;
            float z = bA[idx];
            if (bB) z += bB[idx];
            c_lds[rr][kk] = __expf(z - mk) / red2[kk];
        }
        __syncthreads();
#pragma unroll
        for (int ri = 0; ri < 9; ++ri) ccc[ri] = c_lds[w * 9 + ri][k];
    };

    // ---- iteration 0: softmax(0) == 1/R exactly ----
#pragma unroll
    for (int ri = 0; ri < 9; ++ri) ccc[ri] = (1.0f / 4608.0f);
    do_sred(s0);
    grid.sync();

    compute_v(s0);
    do_agree(bij0);
    grid.sync();

    // ---- iteration 1 ----
    do_softmax(bij0, (const float*)nullptr);
    do_sred(s1);
    grid.sync();

    compute_v(s1);
    do_agree(bij1);
    grid.sync();

    // ---- iteration 2 (b = bij0 + bij1) ----
    do_softmax(bij0, bij1);
    do_sred(s2);
    grid.sync();

    compute_v(s2);
    if (rg == 0) {   // 4 waves (one per bg) write the 8192 outputs
#pragma unroll
        for (int bl = 0; bl < 32; ++bl) out[(b0 + bl) * 64 + lane] = vv[bl];
    }
}

extern "C" void kernel_launch(void* const* d_in, const int* in_sizes, int n_in,
                              void* d_out, int out_size, void* d_ws, size_t ws_size,
                              hipStream_t stream) {
    const float* x = (const float*)d_in[0];   // [128,4608,16]
    const float* W = (const float*)d_in[1];   // [1,4608,2,32,16]
    float* out = (float*)d_out;               // [128,2,32]
    float* ws  = (float*)d_ws;

    void* args[] = { (void*)&x, (void*)&W, (void*)&out, (void*)&ws };
    hipLaunchCooperativeKernel((void*)caps_mega, dim3(256), dim3(512), args, 0, stream);
}

// Round 4
// 1669.395 us; speedup vs baseline: 1.1686x; 1.1686x over previous
//
#include <hip/hip_runtime.h>
#include <hip/hip_cooperative_groups.h>
#include <math.h>

namespace cg = cooperative_groups;

// B=128, R=4608, K=2, O=32, I=16.
// 256 blocks x 1024 threads (16 waves, 1 block/CU — cooperative-safe grid).
// Block = (bg 0..7, rgB 0..31). Thread: lane=ko (k=lane>>5, o=lane&31), wave w=0..15.
// Thread owns 16 b (bg*16.., bf16 pairs: lo=even b) x 9 r (rgB*144 + w*9 ..+8).
// ws float layout: s0,s1,s2 [128*64]; bij0,bij1 [4608*2]
#define S_SZ   8192
#define BIJ_SZ 9216

__device__ __forceinline__ float bf_lo(unsigned p) { return __uint_as_float(p << 16); }
__device__ __forceinline__ float bf_hi(unsigned p) { return __uint_as_float(p & 0xffff0000u); }
__device__ __forceinline__ unsigned pack_bf16(float a, float b) {
    unsigned ua = __float_as_uint(a);
    unsigned ub = __float_as_uint(b);
    ua += 0x7fffu + ((ua >> 16) & 1u);   // RNE
    ub += 0x7fffu + ((ub >> 16) & 1u);
    return (ua >> 16) | (ub & 0xffff0000u);
}

__device__ __forceinline__ float dot16(const float4 w0, const float4 w1,
                                       const float4 w2, const float4 w3,
                                       const float* __restrict__ xp) {
    float4 a0 = *(const float4*)(xp + 0);
    float4 a1 = *(const float4*)(xp + 4);
    float4 a2 = *(const float4*)(xp + 8);
    float4 a3 = *(const float4*)(xp + 12);
    return w0.x*a0.x + w0.y*a0.y + w0.z*a0.z + w0.w*a0.w
         + w1.x*a1.x + w1.y*a1.y + w1.z*a1.z + w1.w*a1.w
         + w2.x*a2.x + w2.y*a2.y + w2.z*a2.z + w2.w*a2.w
         + w3.x*a3.x + w3.y*a3.y + w3.z*a3.z + w3.w*a3.w;
}

__global__ __launch_bounds__(1024, 4) void caps_mega(
    const float* __restrict__ x, const float* __restrict__ W,
    float* __restrict__ out, float* __restrict__ ws)
{
    __shared__ float sredL[16 * 16 * 64];   // 64 KB: [wave-b row 0..255][lane]
    __shared__ float red2[1024];
    __shared__ float c_lds[144][2];

    float* s0 = ws;
    float* s1 = ws + S_SZ;
    float* s2 = ws + 2 * S_SZ;
    float* bij0 = ws + 3 * S_SZ;
    float* bij1 = ws + 3 * S_SZ + BIJ_SZ;

    const int t    = threadIdx.x;
    const int lane = t & 63;
    const int w    = t >> 6;           // 0..15
    const int bk   = blockIdx.x;
    const int bg   = bk >> 5;          // 0..7  -> 16-b range
    const int rgB  = bk & 31;          // 0..31 -> 144-r range
    const int b0   = bg * 16;
    const int r0   = rgB * 144 + w * 9;
    const int k    = lane >> 5;
    const int o    = lane & 31;

    // zero s0..s2 + bij0..bij1 (ws is poisoned 0xAA before every launch)
    {
        int i = bk * 1024 + t;
        if (i < 3 * S_SZ + 2 * BIJ_SZ) ws[i] = 0.0f;
    }

    // ---- phase 0: u_hat[b,r,ko] into registers (bf16 pairs: lo=even b) ----
    unsigned u2[72];   // [ri][bp]: 9 r x 8 b-pairs
    {
        const float* Wbase = W + (size_t)r0 * 1024 + (size_t)lane * 16;
        const float* xbase = x + ((size_t)b0 * 4608 + (size_t)r0) * 16;
#pragma unroll
        for (int ri = 0; ri < 9; ++ri) {
            float4 w0 = *(const float4*)(Wbase + ri * 1024 + 0);
            float4 w1 = *(const float4*)(Wbase + ri * 1024 + 4);
            float4 w2 = *(const float4*)(Wbase + ri * 1024 + 8);
            float4 w3 = *(const float4*)(Wbase + ri * 1024 + 12);
#pragma unroll
            for (int bp = 0; bp < 8; ++bp) {
                const float* xp = xbase + ((size_t)(2 * bp) * 4608 + ri) * 16;
                const float* xq = xp + (size_t)4608 * 16;
                float accA = dot16(w0, w1, w2, w3, xp);
                float accB = dot16(w0, w1, w2, w3, xq);
                u2[ri * 8 + bp] = pack_bf16(accA, accB);
            }
        }
    }

    cg::grid_group grid = cg::this_grid();
    grid.sync();   // zeroing visible before any atomic accumulation

    float ccc[9];

    // s[b,ko] += sum_r c[r,k]*u : 9 r in-reg (bp-outer, 2 accs), 16 waves via LDS,
    // 32 rgB-blocks via atomics
    auto do_sred = [&](float* __restrict__ sG) {
#pragma unroll
        for (int bp = 0; bp < 8; ++bp) {
            float a0 = 0.0f, a1 = 0.0f;
#pragma unroll
            for (int ri = 0; ri < 9; ++ri) {
                unsigned p = u2[ri * 8 + bp];
                a0 = fmaf(ccc[ri], bf_lo(p), a0);
                a1 = fmaf(ccc[ri], bf_hi(p), a1);
            }
            sredL[(w * 16 + 2 * bp) * 64 + lane]     = a0;
            sredL[(w * 16 + 2 * bp + 1) * 64 + lane] = a1;
        }
        __syncthreads();
        {
            float acc = 0.0f;
#pragma unroll
            for (int ww = 0; ww < 16; ++ww) acc += sredL[ww * 1024 + t];
            atomicAdd(&sG[b0 * 64 + t], acc);
        }
        __syncthreads();
    };

    // fused squash + agreement (bp-outer, no vv[] array):
    // v[b,ko] from global s (shuffle sn over the 32 o-lanes of this k-half), then
    // bij[r,k] += (1/B) sum_b sum_o u*v : 16 b in-reg, 32 o via shuffle, 8 bg via atomics
    auto do_agree = [&](const float* __restrict__ sG, float* __restrict__ bijG) {
        float pacc[9];
#pragma unroll
        for (int ri = 0; ri < 9; ++ri) pacc[ri] = 0.0f;
#pragma unroll
        for (int bp = 0; bp < 8; ++bp) {
            float sv0 = sG[(b0 + 2 * bp) * 64 + lane];
            float sv1 = sG[(b0 + 2 * bp + 1) * 64 + lane];
            float p0 = sv0 * sv0, p1 = sv1 * sv1;
#pragma unroll
            for (int m = 16; m > 0; m >>= 1) {   // stays within each 32-lane k-half
                p0 += __shfl_xor(p0, m, 64);
                p1 += __shfl_xor(p1, m, 64);
            }
            float v0 = sv0 * (p0 / ((0.5f + p0) * sqrtf(p0)));
            float v1 = sv1 * (p1 / ((0.5f + p1) * sqrtf(p1)));
#pragma unroll
            for (int ri = 0; ri < 9; ++ri) {
                unsigned p = u2[ri * 8 + bp];
                pacc[ri] = fmaf(bf_lo(p), v0, pacc[ri]);
                pacc[ri] = fmaf(bf_hi(p), v1, pacc[ri]);
            }
        }
#pragma unroll
        for (int ri = 0; ri < 9; ++ri) {
            float p = pacc[ri];
#pragma unroll
            for (int m = 16; m > 0; m >>= 1) p += __shfl_xor(p, m, 64);
            if (o == 0) atomicAdd(&bijG[(r0 + ri) * 2 + k], p * (1.0f / 128.0f));
        }
    };

    // per-block redundant softmax over R (z = bA [+ bB]); fills ccc
    auto do_softmax = [&](const float* __restrict__ bA, const float* __restrict__ bB) {
        float zloc[9];
        float m = -1e30f;
#pragma unroll
        for (int j = 0; j < 9; ++j) {
            int idx = t + j * 1024;
            float z = bA[idx];
            if (bB) z += bB[idx];
            zloc[j] = z;
            m = fmaxf(m, z);
        }
        red2[t] = m;
        __syncthreads();
        for (int off = 512; off >= 2; off >>= 1) {   // parity-preserving tree (k = idx&1)
            if (t < off) red2[t] = fmaxf(red2[t], red2[t + off]);
            __syncthreads();
        }
        float mk = red2[t & 1];
        __syncthreads();
        float ssum = 0.0f;
#pragma unroll
        for (int j = 0; j < 9; ++j) ssum += __expf(zloc[j] - mk);
        red2[t] = ssum;
        __syncthreads();
        for (int off = 512; off >= 2; off >>= 1) {
            if (t < off) red2[t] += red2[t + off];
            __syncthreads();
        }
        if (t < 288) {
            int rr = t >> 1, kk = t & 1;          // kk == t&1 == parity used for mk
            int idx = (rgB * 144 + rr) * 2 + kk;
            float z = bA[idx];
            if (bB) z += bB[idx];
            c_lds[rr][kk] = __expf(z - mk) / red2[kk];
        }
        __syncthreads();
#pragma unroll
        for (int ri = 0; ri < 9; ++ri) ccc[ri] = c_lds[w * 9 + ri][k];
        __syncthreads();
    };

    // ---- iteration 0: softmax(0) == 1/R exactly ----
#pragma unroll
    for (int ri = 0; ri < 9; ++ri) ccc[ri] = (1.0f / 4608.0f);
    do_sred(s0);
    grid.sync();

    do_agree(s0, bij0);
    grid.sync();

    // ---- iteration 1 ----
    do_softmax(bij0, (const float*)nullptr);
    do_sred(s1);
    grid.sync();

    do_agree(s1, bij1);
    grid.sync();

    // ---- iteration 2 (b = bij0 + bij1) ----
    do_softmax(bij0, bij1);
    do_sred(s2);
    grid.sync();

    // final v = squash(s2); 8 writer blocks (rgB==0), wave 0 each
    if (rgB == 0 && w == 0) {
#pragma unroll
        for (int bl = 0; bl < 16; ++bl) {
            float sv = s2[(b0 + bl) * 64 + lane];
            float p = sv * sv;
#pragma unroll
            for (int m = 16; m > 0; m >>= 1) p += __shfl_xor(p, m, 64);
            float f = p / ((0.5f + p) * sqrtf(p));
            out[(b0 + bl) * 64 + lane] = sv * f;
        }
    }
}

extern "C" void kernel_launch(void* const* d_in, const int* in_sizes, int n_in,
                              void* d_out, int out_size, void* d_ws, size_t ws_size,
                              hipStream_t stream) {
    const float* x = (const float*)d_in[0];   // [128,4608,16]
    const float* W = (const float*)d_in[1];   // [1,4608,2,32,16]
    float* out = (float*)d_out;               // [128,2,32]
    float* ws  = (float*)d_ws;

    void* args[] = { (void*)&x, (void*)&W, (void*)&out, (void*)&ws };
    hipLaunchCooperativeKernel((void*)caps_mega, dim3(256), dim3(1024), args, 0, stream);
}